// Round 11
// baseline (1632.531 us; speedup 1.0000x reference)
//
#include <hip/hip_runtime.h>
#include <hip/hip_fp16.h>
#include <hip/hip_cooperative_groups.h>
#include <math.h>

namespace cg = cooperative_groups;

#define N_NODES 100000
#define N_EDGES 1600000
#define IN_F 128
#define OUT_F 64
#define NEG_SLOPE 0.2f

#define NBUCK 391          // ceil(N_NODES / 256): bucket = 256 consecutive node ids
#define PB 512             // edge-slice blocks for hist/scatter
#define EPB (N_EDGES / PB) // 3125 edges per slice

#define FS 132             // LDS row stride (uints) for packed W tile
#define BCAP 5120          // k_bucket csr staging cap (records); avg bucket ~4096
#define NGB 1563           // ceil(N_NODES / 64) gemm blocks

typedef __attribute__((ext_vector_type(8))) short short8;
typedef __attribute__((ext_vector_type(4))) float f32x4;

// split f32 -> bf16 hi/lo packed in one uint: (hi16<<16)|lo16, x ~= hi + lo
__device__ __forceinline__ unsigned pack_bf(float f) {
    unsigned u  = __float_as_uint(f);
    unsigned hi = u & 0xffff0000u;
    float    lo = f - __uint_as_float(hi);
    return hi | (__float_as_uint(lo) >> 16);
}

__device__ __forceinline__ void unpack8(uint4 p0, uint4 p1, short8& hi, short8& lo) {
    hi[0] = (short)(p0.x >> 16); lo[0] = (short)(p0.x & 0xffffu);
    hi[1] = (short)(p0.y >> 16); lo[1] = (short)(p0.y & 0xffffu);
    hi[2] = (short)(p0.z >> 16); lo[2] = (short)(p0.z & 0xffffu);
    hi[3] = (short)(p0.w >> 16); lo[3] = (short)(p0.w & 0xffffu);
    hi[4] = (short)(p1.x >> 16); lo[4] = (short)(p1.x & 0xffffu);
    hi[5] = (short)(p1.y >> 16); lo[5] = (short)(p1.y & 0xffffu);
    hi[6] = (short)(p1.z >> 16); lo[6] = (short)(p1.z & 0xffffu);
    hi[7] = (short)(p1.w >> 16); lo[7] = (short)(p1.w & 0xffffu);
}

// ---------------- fused GEMM + histograms (r10 form, proven) ----------------------
__global__ __launch_bounds__(256) void k_gemm_hist(
        const float* __restrict__ feat, const float* __restrict__ W,
        const float* __restrict__ attn_l, const float* __restrict__ attn_r,
        __half* __restrict__ h16, float* __restrict__ el, float* __restrict__ er,
        const int* __restrict__ src, const int* __restrict__ dst,
        int* __restrict__ cntd, int* __restrict__ cnts) {
    __shared__ __align__(16) unsigned smem[64 * FS];   // 33.8 KB: W tile / hist cnts
    int t = threadIdx.x;

    if (blockIdx.x >= NGB) {
        // ---------------- histogram branch (dst AND src), int4 edge loads --------
        int* hd = (int*)smem;
        int* hs = hd + NBUCK;
        int b = blockIdx.x - NGB;
        for (int k = t; k < NBUCK; k += 256) { hd[k] = 0; hs[k] = 0; }
        __syncthreads();
        int base = b * EPB, end = base + EPB;
        int a0 = (base + 3) & ~3;              // first 16B-aligned index
        int a1 = end & ~3;                     // aligned end
        if (t < a0 - base) {
            int i = base + t;
            atomicAdd(&hd[dst[i] >> 8], 1);
            atomicAdd(&hs[src[i] >> 8], 1);
        }
        for (int i = a0 + 4 * t; i < a1; i += 1024) {
            int4 d4 = *(const int4*)&dst[i];
            int4 s4 = *(const int4*)&src[i];
            atomicAdd(&hd[d4.x >> 8], 1); atomicAdd(&hd[d4.y >> 8], 1);
            atomicAdd(&hd[d4.z >> 8], 1); atomicAdd(&hd[d4.w >> 8], 1);
            atomicAdd(&hs[s4.x >> 8], 1); atomicAdd(&hs[s4.y >> 8], 1);
            atomicAdd(&hs[s4.z >> 8], 1); atomicAdd(&hs[s4.w >> 8], 1);
        }
        if (t < end - a1) {
            int i = a1 + t;
            atomicAdd(&hd[dst[i] >> 8], 1);
            atomicAdd(&hs[src[i] >> 8], 1);
        }
        __syncthreads();
        for (int k = t; k < NBUCK; k += 256) {
            cntd[k * PB + b] = hd[k];
            cnts[k * PB + b] = hs[k];
        }
        return;
    }

    // ---------------- GEMM branch: h(fp16) = feat@W^T, fused el/er ---------------
    unsigned* wlds = smem;                     // 64 outf x 128 k, packed
    int n0 = blockIdx.x * 64;

    int lane = t & 63, wv_ = t >> 6;
    int quad = lane >> 4, nl = lane & 15;
    int mrow = wv_ * 16 + nl;                  // A-operand node row for this lane
    int g = n0 + mrow;

    // issue all A-fragment loads up front (latency overlaps W staging below)
    const float* frow = &feat[(size_t)g * IN_F];
    float4 fa[4][2];
    #pragma unroll
    for (int ks = 0; ks < 4; ++ks) {
        int ko = ks * 32 + quad * 8;
        if (g < N_NODES) {
            fa[ks][0] = *(const float4*)(frow + ko);
            fa[ks][1] = *(const float4*)(frow + ko + 4);
        } else {
            fa[ks][0] = (float4){0.f, 0.f, 0.f, 0.f};
            fa[ks][1] = (float4){0.f, 0.f, 0.f, 0.f};
        }
    }

    #pragma unroll
    for (int j = 0; j < 8; ++j) {              // 2048 float4-quads for W
        int idx = t + j * 256;
        int row = idx >> 5, k4 = (idx & 31) * 4;
        float4 wv = *(const float4*)&W[row * IN_F + k4];
        unsigned* wp = &wlds[row * FS + k4];
        wp[0] = pack_bf(wv.x); wp[1] = pack_bf(wv.y);
        wp[2] = pack_bf(wv.z); wp[3] = pack_bf(wv.w);
    }
    __syncthreads();

    f32x4 acc[4];
    #pragma unroll
    for (int nt = 0; nt < 4; ++nt) acc[nt] = (f32x4){0.f, 0.f, 0.f, 0.f};

    #pragma unroll
    for (int ks = 0; ks < 4; ++ks) {
        int ko = ks * 32 + quad * 8;
        float ff[8] = {fa[ks][0].x, fa[ks][0].y, fa[ks][0].z, fa[ks][0].w,
                       fa[ks][1].x, fa[ks][1].y, fa[ks][1].z, fa[ks][1].w};
        short8 ahi, alo;
        #pragma unroll
        for (int q2 = 0; q2 < 8; ++q2) {
            unsigned u  = __float_as_uint(ff[q2]);
            unsigned hi = u & 0xffff0000u;
            float    lo = ff[q2] - __uint_as_float(hi);
            ahi[q2] = (short)(hi >> 16);
            alo[q2] = (short)(__float_as_uint(lo) >> 16);
        }
        #pragma unroll
        for (int nt = 0; nt < 4; ++nt) {
            const uint4* bp = (const uint4*)&wlds[(nt * 16 + nl) * FS + ko];
            uint4 b0 = bp[0], b1 = bp[1];
            short8 bhi, blo; unpack8(b0, b1, bhi, blo);
            acc[nt] = __builtin_amdgcn_mfma_f32_16x16x32_bf16(ahi, bhi, acc[nt], 0, 0, 0);
            acc[nt] = __builtin_amdgcn_mfma_f32_16x16x32_bf16(ahi, blo, acc[nt], 0, 0, 0);
            acc[nt] = __builtin_amdgcn_mfma_f32_16x16x32_bf16(alo, bhi, acc[nt], 0, 0, 0);
        }
    }

    float al4[4], ar4[4];
    #pragma unroll
    for (int nt = 0; nt < 4; ++nt) { al4[nt] = attn_l[nt * 16 + nl]; ar4[nt] = attn_r[nt * 16 + nl]; }
    float elp[4] = {0.f, 0.f, 0.f, 0.f}, erp[4] = {0.f, 0.f, 0.f, 0.f};
    #pragma unroll
    for (int nt = 0; nt < 4; ++nt)
        #pragma unroll
        for (int r = 0; r < 4; ++r) {
            elp[r] += acc[nt][r] * al4[nt];
            erp[r] += acc[nt][r] * ar4[nt];
        }
    #pragma unroll
    for (int off = 1; off <= 8; off <<= 1)
        #pragma unroll
        for (int r = 0; r < 4; ++r) {
            elp[r] += __shfl_xor(elp[r], off);
            erp[r] += __shfl_xor(erp[r], off);
        }
    int gbase = n0 + wv_ * 16 + quad * 4;
    if (nl == 0) {
        #pragma unroll
        for (int r = 0; r < 4; ++r) {
            int gg = gbase + r;
            if (gg < N_NODES) { el[gg] = elp[r]; er[gg] = erp[r]; }
        }
    }
    #pragma unroll
    for (int r = 0; r < 4; ++r) {
        int gg = gbase + r;
        if (gg < N_NODES) {
            #pragma unroll
            for (int nt = 0; nt < 4; ++nt)
                h16[(size_t)gg * OUT_F + nt * 16 + nl] = __float2half(acc[nt][r]);
        }
    }
}

// ---------------- cooperative: colsum + bstart + blockoff in one ------------------
// v11: three tiny serialized kernels -> one cooperative dispatch. Phase 1: each of
// 782 blocks inclusive-scans its count row (row total = s[511], replacing colsum's
// tree). grid.sync. Phase 2: scan the 391 bucket totals in LDS, apply global base.
// Outputs bit-identical to colsum/bstart/blockoff.
__global__ __launch_bounds__(512) void k_offsets(
        int* cntd, int* cnts, int* totd, int* tots,
        int* bstartd, int* bstarts) {
    cg::grid_group grid = cg::this_grid();
    __shared__ int s[512];
    __shared__ int tsc[512];
    int b = blockIdx.x, t = threadIdx.x;
    int* m; int* tot; int k;
    if (b < NBUCK) { m = cntd; tot = totd; k = b; }
    else           { m = cnts; tot = tots; k = b - NBUCK; }
    int c = m[k * PB + t];
    s[t] = c; __syncthreads();
    for (int d = 1; d < 512; d <<= 1) {
        int a = (t >= d) ? s[t - d] : 0; __syncthreads();
        s[t] += a; __syncthreads();
    }
    if (t == 511) tot[k] = s[511];
    int myexcl = s[t] - c;                     // kept in register across sync
    __threadfence();
    grid.sync();
    const int* ts = (b < NBUCK) ? totd : tots;
    int v = (t < NBUCK) ? ts[t] : 0;
    tsc[t] = v; __syncthreads();
    for (int d = 1; d < 512; d <<= 1) {
        int a = (t >= d) ? tsc[t - d] : 0; __syncthreads();
        tsc[t] += a; __syncthreads();
    }
    int bs = (k > 0) ? tsc[k - 1] : 0;
    m[k * PB + t] = bs + myexcl;
    if (b == 0     && t <= NBUCK) bstartd[t] = tsc[t] - v;   // v==0 at t==NBUCK
    if (b == NBUCK && t <= NBUCK) bstarts[t] = tsc[t] - v;
}

// fallback trio (r10-proven) -------------------------------------------------------
__global__ __launch_bounds__(256) void k_colsum(const int* __restrict__ cntd,
                                                const int* __restrict__ cnts,
                                                int* __restrict__ totd,
                                                int* __restrict__ tots) {
    __shared__ int s[256];
    int b = blockIdx.x, t = threadIdx.x;
    const int* m; int* o; int k;
    if (b < NBUCK) { m = cntd; o = totd; k = b; }
    else           { m = cnts; o = tots; k = b - NBUCK; }
    s[t] = m[k * PB + t] + m[k * PB + t + 256];
    __syncthreads();
    for (int d = 128; d; d >>= 1) { if (t < d) s[t] += s[t + d]; __syncthreads(); }
    if (t == 0) o[k] = s[0];
}

__global__ __launch_bounds__(512) void k_bstart(const int* __restrict__ totd,
                                                const int* __restrict__ tots,
                                                int* bstartd, int* bstarts) {
    __shared__ int s[512];
    int t = threadIdx.x;
    int v = (t < NBUCK) ? totd[t] : 0;
    s[t] = v; __syncthreads();
    for (int d = 1; d < 512; d <<= 1) { int a = (t >= d) ? s[t - d] : 0; __syncthreads(); s[t] += a; __syncthreads(); }
    if (t <= NBUCK) bstartd[t] = s[t] - v;
    __syncthreads();
    int v2 = (t < NBUCK) ? tots[t] : 0;
    s[t] = v2; __syncthreads();
    for (int d = 1; d < 512; d <<= 1) { int a = (t >= d) ? s[t - d] : 0; __syncthreads(); s[t] += a; __syncthreads(); }
    if (t <= NBUCK) bstarts[t] = s[t] - v2;
}

__global__ __launch_bounds__(512) void k_blockoff(const int* __restrict__ bstartd,
                                                  const int* __restrict__ bstarts,
                                                  int* cntd, int* cnts) {
    __shared__ int s[512];
    int b = blockIdx.x, t = threadIdx.x;
    int* m; const int* bs; int k;
    if (b < NBUCK) { m = cntd; bs = bstartd; k = b; }
    else           { m = cnts; bs = bstarts; k = b - NBUCK; }
    int c = m[k * PB + t];
    s[t] = c; __syncthreads();
    for (int d = 1; d < 512; d <<= 1) { int a = (t >= d) ? s[t - d] : 0; __syncthreads(); s[t] += a; __syncthreads(); }
    m[k * PB + t] = bs[k] + s[t] - c;
}

// ---------------- merged scatter: LDS dense staging + coalesced copy-out ----------
__global__ __launch_bounds__(256) void k_scatter3(
        const int* __restrict__ src, const int* __restrict__ dst,
        const float* __restrict__ el, const float* __restrict__ er,
        const int* __restrict__ offd, const int* __restrict__ offs,
        int2* __restrict__ tmpd, unsigned char* __restrict__ tmps) {
    __shared__ int gOffD[NBUCK], gOffS[NBUCK];
    __shared__ int hD[NBUCK], hS[NBUCK];
    __shared__ int fD[NBUCK], fS[NBUCK];
    __shared__ int sD[512], sS[512];
    __shared__ int2 stD[EPB];
    __shared__ unsigned char stS[EPB];
    int t = threadIdx.x, b = blockIdx.x;
    for (int k = t; k < NBUCK; k += 256) {
        gOffD[k] = offd[k * PB + b]; gOffS[k] = offs[k * PB + b];
        hD[k] = 0; hS[k] = 0; fD[k] = 0; fS[k] = 0;
    }
    __syncthreads();
    int base = b * EPB;
    for (int i = t; i < EPB; i += 256) {
        atomicAdd(&hD[dst[base + i] >> 8], 1);
        atomicAdd(&hS[src[base + i] >> 8], 1);
    }
    __syncthreads();
    sD[t]       = (t < NBUCK) ? hD[t] : 0;
    sD[t + 256] = (t + 256 < NBUCK) ? hD[t + 256] : 0;
    sS[t]       = (t < NBUCK) ? hS[t] : 0;
    sS[t + 256] = (t + 256 < NBUCK) ? hS[t + 256] : 0;
    __syncthreads();
    for (int d = 1; d < 512; d <<= 1) {
        int a0 = (t >= d) ? sD[t - d] : 0;
        int a1 = sD[t + 256 - d];
        int b0 = (t >= d) ? sS[t - d] : 0;
        int b1 = sS[t + 256 - d];
        __syncthreads();
        sD[t] += a0; sD[t + 256] += a1;
        sS[t] += b0; sS[t + 256] += b1;
        __syncthreads();
    }
    for (int k = t; k < NBUCK; k += 256) {
        hD[k] = sD[k] - hD[k];
        hS[k] = sS[k] - hS[k];
    }
    __syncthreads();
    for (int i = t; i < EPB; i += 256) {
        int e = base + i;
        int sN = src[e], dN = dst[e];
        int ks = sN >> 8;
        int rs = atomicAdd(&fS[ks], 1);
        stS[hS[ks] + rs] = (unsigned char)(sN & 255);
        float v = el[sN] + er[dN];
        v = (v > 0.f) ? v : NEG_SLOPE * v;
        float pe = __expf(v);
        int kd = dN >> 8;
        int rd = atomicAdd(&fD[kd], 1);
        int2 rec; rec.x = sN | ((dN & 255) << 17); rec.y = __float_as_int(pe);
        stD[hD[kd] + rd] = rec;
    }
    __syncthreads();
    for (int j = t; j < EPB; j += 256) {
        int k = 0;
        #pragma unroll
        for (int step = 256; step > 0; step >>= 1) {
            int c = k + step;
            if (c <= 511 && sD[c - 1] <= j) k = c;
        }
        tmpd[gOffD[k] + (j - hD[k])] = stD[j];
        int k2 = 0;
        #pragma unroll
        for (int step = 256; step > 0; step >>= 1) {
            int c = k2 + step;
            if (c <= 511 && sS[c - 1] <= j) k2 = c;
        }
        tmps[gOffS[k2] + (j - hS[k2])] = stS[j];
    }
}

// ---------------- cooperative: srccnt + bucket in one -----------------------------
// v11: srccnt's onorm must be globally complete before bucket reads onorm[sN] for
// arbitrary buckets -> grid.sync between the phases. 45.2KB LDS -> 3 blocks/CU,
// 391 blocks co-resident. Bit-identical to the two-kernel version.
__global__ __launch_bounds__(256) void k_finish(
        const unsigned char* tmps, const int* bstarts,
        const int2* tmpd, const int* bstartd,
        float* onorm, float2* csr, int* rowstart, float* sigma) {
    cg::grid_group grid = cg::this_grid();
    __shared__ int   cnt[256];
    __shared__ int   cs[256];
    __shared__ int   excl[256];
    __shared__ int   fill[256];
    __shared__ float dsum[256];
    __shared__ float2 stC[BCAP];
    int k = blockIdx.x, t = threadIdx.x;

    // phase 1: src-bucket count -> onorm
    cnt[t] = 0; __syncthreads();
    {
        int base = bstarts[k], end = bstarts[k + 1];
        for (int i = base + t; i < end; i += 256)
            atomicAdd(&cnt[tmps[i]], 1);
    }
    __syncthreads();
    int idx = k * 256 + t;
    if (idx < N_NODES) onorm[idx] = rsqrtf((float)max(cnt[t], 1));
    __threadfence();
    grid.sync();

    // phase 2: per-bucket fine sort -> CSR, sigma
    int base = bstartd[k], end = bstartd[k + 1];
    int tot = end - base;
    bool staged = (tot <= BCAP);
    cs[t] = 0; fill[t] = 0; dsum[t] = 0.f;
    __syncthreads();
    for (int i = base + t; i < end; i += 256)
        atomicAdd(&cs[(tmpd[i].x >> 17) & 255], 1);
    __syncthreads();
    int c = cs[t];
    for (int d = 1; d < 256; d <<= 1) {
        int a = (t >= d) ? cs[t - d] : 0;
        __syncthreads();
        cs[t] += a;
        __syncthreads();
    }
    excl[t] = cs[t] - c;
    __syncthreads();
    if (idx <= N_NODES) rowstart[idx] = base + excl[t];
    for (int i = base + t; i < end; i += 256) {
        int2 rec = tmpd[i];
        int dlow = (rec.x >> 17) & 255;
        int r = atomicAdd(&fill[dlow], 1);
        float pe = __int_as_float(rec.y);
        int sN = rec.x & 131071;
        float2 w;
        w.x = __int_as_float(sN);
        w.y = pe * onorm[sN];
        int pos = excl[dlow] + r;
        if (staged) stC[pos] = w;
        else        csr[base + pos] = w;
        atomicAdd(&dsum[dlow], pe);
    }
    __syncthreads();
    if (staged)
        for (int j = t; j < tot; j += 256)
            csr[base + j] = stC[j];
    if (idx < N_NODES) {
        float inn = sqrtf((float)max(c, 1));
        sigma[idx] = (c > 0) ? inn / dsum[t] : 0.f;
    }
}

// fallback pair --------------------------------------------------------------------
__global__ __launch_bounds__(256) void k_srccnt(
        const unsigned char* __restrict__ tmps, const int* __restrict__ bstarts,
        float* __restrict__ onorm) {
    __shared__ int cnt[256];
    int k = blockIdx.x, t = threadIdx.x;
    cnt[t] = 0; __syncthreads();
    int base = bstarts[k], end = bstarts[k + 1];
    for (int i = base + t; i < end; i += 256)
        atomicAdd(&cnt[tmps[i]], 1);
    __syncthreads();
    int idx = k * 256 + t;
    if (idx < N_NODES) onorm[idx] = rsqrtf((float)max(cnt[t], 1));
}

__global__ __launch_bounds__(256) void k_bucket(
        const int2* __restrict__ tmp, const int* __restrict__ bstart,
        const float* __restrict__ onorm, float2* __restrict__ csr,
        int* __restrict__ rowstart, float* __restrict__ sigma) {
    __shared__ int   cs[256];
    __shared__ int   excl[256];
    __shared__ int   fill[256];
    __shared__ float dsum[256];
    __shared__ float2 stC[BCAP];
    int k = blockIdx.x, t = threadIdx.x;
    int base = bstart[k], end = bstart[k + 1];
    int tot = end - base;
    bool staged = (tot <= BCAP);
    cs[t] = 0; fill[t] = 0; dsum[t] = 0.f;
    __syncthreads();
    for (int i = base + t; i < end; i += 256)
        atomicAdd(&cs[(tmp[i].x >> 17) & 255], 1);
    __syncthreads();
    int c = cs[t];
    for (int d = 1; d < 256; d <<= 1) {
        int a = (t >= d) ? cs[t - d] : 0;
        __syncthreads();
        cs[t] += a;
        __syncthreads();
    }
    excl[t] = cs[t] - c;
    __syncthreads();
    int idx = k * 256 + t;
    if (idx <= N_NODES) rowstart[idx] = base + excl[t];
    for (int i = base + t; i < end; i += 256) {
        int2 rec = tmp[i];
        int dlow = (rec.x >> 17) & 255;
        int r = atomicAdd(&fill[dlow], 1);
        float pe = __int_as_float(rec.y);
        int sN = rec.x & 131071;
        float2 w;
        w.x = __int_as_float(sN);
        w.y = pe * onorm[sN];
        int pos = excl[dlow] + r;
        if (staged) stC[pos] = w;
        else        csr[base + pos] = w;
        atomicAdd(&dsum[dlow], pe);
    }
    __syncthreads();
    if (staged)
        for (int j = t; j < tot; j += 256)
            csr[base + j] = stC[j];
    if (idx < N_NODES) {
        float inn = sqrtf((float)max(c, 1));
        sigma[idx] = (c > 0) ? inn / dsum[t] : 0.f;
    }
}

// ---------------- SpMM pass body (v3 geometry, proven best) -----------------------
template<typename OT>
__device__ __forceinline__ void spmm_pass(
        const __half* __restrict__ x, const int* __restrict__ rowstart,
        const float2* __restrict__ csr, const float* __restrict__ sigma,
        OT* __restrict__ y) {
    int fl = threadIdx.x & 7;
    for (int nb = blockIdx.x * 32; nb < N_NODES; nb += gridDim.x * 32) {
        int node = nb + (threadIdx.x >> 3);
        if (node >= N_NODES) continue;
        int b = rowstart[node], e = rowstart[node + 1];
        float4 a0lo = {0.f, 0.f, 0.f, 0.f}, a0hi = {0.f, 0.f, 0.f, 0.f};
        float4 a1lo = {0.f, 0.f, 0.f, 0.f}, a1hi = {0.f, 0.f, 0.f, 0.f};
        for (int i = b; i < e; i += 8) {
            #pragma unroll
            for (int u = 0; u < 8; ++u) {
                int j = i + u;
                int jc = (j < e) ? j : (e - 1);
                float2 w = csr[jc];                // 8-lane broadcast (8B)
                float vv = (j < e) ? w.y : 0.f;
                unsigned boff = ((unsigned)__float_as_int(w.x) << 7) | ((unsigned)fl << 4);
                uint4 pk = *(const uint4*)((const char*)x + boff);
                float2 f0 = __half22float2(*(__half2*)&pk.x);
                float2 f1 = __half22float2(*(__half2*)&pk.y);
                float2 f2 = __half22float2(*(__half2*)&pk.z);
                float2 f3 = __half22float2(*(__half2*)&pk.w);
                float4& alo = (u & 1) ? a1lo : a0lo;
                float4& ahi = (u & 1) ? a1hi : a0hi;
                alo.x += vv * f0.x; alo.y += vv * f0.y; alo.z += vv * f1.x; alo.w += vv * f1.y;
                ahi.x += vv * f2.x; ahi.y += vv * f2.y; ahi.z += vv * f3.x; ahi.w += vv * f3.y;
            }
        }
        float sg = sigma[node];
        float4 rlo, rhi;
        rlo.x = sg * (a0lo.x + a1lo.x); rlo.y = sg * (a0lo.y + a1lo.y);
        rlo.z = sg * (a0lo.z + a1lo.z); rlo.w = sg * (a0lo.w + a1lo.w);
        rhi.x = sg * (a0hi.x + a1hi.x); rhi.y = sg * (a0hi.y + a1hi.y);
        rhi.z = sg * (a0hi.z + a1hi.z); rhi.w = sg * (a0hi.w + a1hi.w);
        if constexpr (sizeof(OT) == 4) {
            float* yp = (float*)y + (size_t)node * OUT_F + fl * 8;
            *(float4*)yp       = rlo;
            *(float4*)(yp + 4) = rhi;
        } else {
            __half2 p0 = __floats2half2_rn(rlo.x, rlo.y);
            __half2 p1 = __floats2half2_rn(rlo.z, rlo.w);
            __half2 p2 = __floats2half2_rn(rhi.x, rhi.y);
            __half2 p3 = __floats2half2_rn(rhi.z, rhi.w);
            uint4 o;
            o.x = *(unsigned*)&p0; o.y = *(unsigned*)&p1;
            o.z = *(unsigned*)&p2; o.w = *(unsigned*)&p3;
            *(uint4*)((__half*)y + (size_t)node * OUT_F + fl * 8) = o;
        }
    }
}

// cooperative 3-hop spmm: saves 2 launches/drains; 2048 resident blocks also remove
// the 3125-block tail effect. launch_bounds(256,8) caps VGPR at 64 (body needs ~40)
// so 8 blocks/CU co-residency validates.
__global__ __launch_bounds__(256, 8) void k_spmm3(
        __half* hbuf, const int* rowstart, const float2* csr,
        const float* sigma, __half* A, float* out) {
    cg::grid_group grid = cg::this_grid();
    spmm_pass<__half>(hbuf, rowstart, csr, sigma, A);       // hop 1
    __threadfence(); grid.sync();
    spmm_pass<__half>(A, rowstart, csr, sigma, hbuf);       // hop 2
    __threadfence(); grid.sync();
    spmm_pass<float>(hbuf, rowstart, csr, sigma, out);      // hop 3
}

// fallback single-hop kernel -------------------------------------------------------
template<typename OT>
__global__ __launch_bounds__(256) void k_spmm(
        const __half* __restrict__ x, const int* __restrict__ rowstart,
        const float2* __restrict__ csr, const float* __restrict__ sigma,
        OT* __restrict__ y) {
    spmm_pass<OT>(x, rowstart, csr, sigma, y);
}

extern "C" void kernel_launch(void* const* d_in, const int* in_sizes, int n_in,
                              void* d_out, int out_size, void* d_ws, size_t ws_size,
                              hipStream_t stream) {
    const float* feat   = (const float*)d_in[0];
    const float* W      = (const float*)d_in[1];
    const float* attn_l = (const float*)d_in[2];
    const float* attn_r = (const float*)d_in[3];
    const int*   src    = (const int*)d_in[4];
    const int*   dst    = (const int*)d_in[5];
    float* out = (float*)d_out;

    char* p = (char*)d_ws;
    auto alloc = [&](size_t bytes) {
        void* r = (void*)p;
        p += (bytes + 255) & ~(size_t)255;
        return r;
    };
    // region1: hbuf (fp16, 12.8 MB): gemm out -> hop1 in; then y2 (hop2 out, hop3 in).
    __half* hbuf = (__half*)alloc((size_t)N_NODES * OUT_F * 2);
    // region2 (14.4 MB): tmpd (12.8) + tmps (1.6) until k_finish; then A = y1.
    char* r2 = (char*)alloc((size_t)N_EDGES * 8 + (size_t)N_EDGES);
    int2*  tmpd = (int2*)r2;
    unsigned char* tmps = (unsigned char*)(r2 + (size_t)N_EDGES * 8);
    __half* A   = (__half*)r2;

    float2* csr      = (float2*)alloc((size_t)N_EDGES * 8);        // 12.8 MB
    int*    cntd     = (int*)   alloc((size_t)NBUCK * PB * 4);
    int*    cnts     = (int*)   alloc((size_t)NBUCK * PB * 4);
    int*    totd     = (int*)   alloc(NBUCK * 4);
    int*    tots     = (int*)   alloc(NBUCK * 4);
    int*    bstartd  = (int*)   alloc((NBUCK + 1) * 4);
    int*    bstarts  = (int*)   alloc((NBUCK + 1) * 4);
    int*    rowstart = (int*)   alloc((N_NODES + 1) * 4);
    float*  onorm    = (float*) alloc(N_NODES * 4);
    float*  sigma    = (float*) alloc(N_NODES * 4);
    float*  el       = (float*) alloc(N_NODES * 4);
    float*  er       = (float*) alloc(N_NODES * 4);

    k_gemm_hist<<<NGB + PB, 256, 0, stream>>>(feat, W, attn_l, attn_r, hbuf, el, er,
                                              src, dst, cntd, cnts);

    {   // colsum + bstart + blockoff, cooperative (fallback: r10 trio)
        void* args[] = {&cntd, &cnts, &totd, &tots, &bstartd, &bstarts};
        if (hipLaunchCooperativeKernel((void*)k_offsets, dim3(2 * NBUCK), dim3(512),
                                       args, 0, stream) != hipSuccess) {
            k_colsum  <<<2 * NBUCK, 256, 0, stream>>>(cntd, cnts, totd, tots);
            k_bstart  <<<1,         512, 0, stream>>>(totd, tots, bstartd, bstarts);
            k_blockoff<<<2 * NBUCK, 512, 0, stream>>>(bstartd, bstarts, cntd, cnts);
        }
    }

    k_scatter3<<<PB, 256, 0, stream>>>(src, dst, el, er, cntd, cnts, tmpd, tmps);

    {   // srccnt + bucket, cooperative (fallback: r10 pair)
        void* args[] = {&tmps, &bstarts, &tmpd, &bstartd, &onorm, &csr, &rowstart, &sigma};
        if (hipLaunchCooperativeKernel((void*)k_finish, dim3(NBUCK), dim3(256),
                                       args, 0, stream) != hipSuccess) {
            k_srccnt<<<NBUCK, 256, 0, stream>>>(tmps, bstarts, onorm);
            k_bucket<<<NBUCK, 256, 0, stream>>>(tmpd, bstartd, onorm, csr, rowstart, sigma);
        }
    }

    {   // 3 spmm hops, cooperative (fallback: r10 triple)
        void* args[] = {&hbuf, &rowstart, &csr, &sigma, &A, &out};
        if (hipLaunchCooperativeKernel((void*)k_spmm3, dim3(2048), dim3(256),
                                       args, 0, stream) != hipSuccess) {
            const int nb_spmm = (N_NODES + 31) / 32;
            k_spmm<__half><<<nb_spmm, 256, 0, stream>>>(hbuf, rowstart, csr, sigma, A);
            k_spmm<__half><<<nb_spmm, 256, 0, stream>>>(A, rowstart, csr, sigma, hbuf);
            k_spmm<float> <<<nb_spmm, 256, 0, stream>>>(hbuf, rowstart, csr, sigma, out);
        }
    }
}

// Round 12
// 272.624 us; speedup vs baseline: 5.9882x; 5.9882x over previous
//
#include <hip/hip_runtime.h>
#include <hip/hip_fp16.h>
#include <math.h>

#define N_NODES 100000
#define N_EDGES 1600000
#define IN_F 128
#define OUT_F 64
#define NEG_SLOPE 0.2f

#define NBUCK 391          // ceil(N_NODES / 256): bucket = 256 consecutive node ids
#define PB 512             // edge-slice blocks for hist/scatter
#define EPB (N_EDGES / PB) // 3125 edges per slice

#define FS 132             // LDS row stride (uints) for packed W tile
#define BCAP 5120          // k_bucket csr staging cap (records); avg bucket ~4096
#define NGB 1563           // ceil(N_NODES / 64) gemm blocks

typedef __attribute__((ext_vector_type(8))) short short8;
typedef __attribute__((ext_vector_type(4))) float f32x4;

// split f32 -> bf16 hi/lo packed in one uint: (hi16<<16)|lo16, x ~= hi + lo
__device__ __forceinline__ unsigned pack_bf(float f) {
    unsigned u  = __float_as_uint(f);
    unsigned hi = u & 0xffff0000u;
    float    lo = f - __uint_as_float(hi);
    return hi | (__float_as_uint(lo) >> 16);
}

__device__ __forceinline__ void unpack8(uint4 p0, uint4 p1, short8& hi, short8& lo) {
    hi[0] = (short)(p0.x >> 16); lo[0] = (short)(p0.x & 0xffffu);
    hi[1] = (short)(p0.y >> 16); lo[1] = (short)(p0.y & 0xffffu);
    hi[2] = (short)(p0.z >> 16); lo[2] = (short)(p0.z & 0xffffu);
    hi[3] = (short)(p0.w >> 16); lo[3] = (short)(p0.w & 0xffffu);
    hi[4] = (short)(p1.x >> 16); lo[4] = (short)(p1.x & 0xffffu);
    hi[5] = (short)(p1.y >> 16); lo[5] = (short)(p1.y & 0xffffu);
    hi[6] = (short)(p1.z >> 16); lo[6] = (short)(p1.z & 0xffffu);
    hi[7] = (short)(p1.w >> 16); lo[7] = (short)(p1.w & 0xffffu);
}

// ---------------- fused GEMM + histograms (r10 form, proven) ----------------------
// r11 lesson: __launch_bounds__(...,8) VGPR-capped spmm to 32 regs -> scratch spill
// -> 12x regression; cooperative launches also added ~270us overhead in this
// graph-captured harness. Reverted wholesale to the r10-proven structure.
__global__ __launch_bounds__(256) void k_gemm_hist(
        const float* __restrict__ feat, const float* __restrict__ W,
        const float* __restrict__ attn_l, const float* __restrict__ attn_r,
        __half* __restrict__ h16, float* __restrict__ el, float* __restrict__ er,
        const int* __restrict__ src, const int* __restrict__ dst,
        int* __restrict__ cntd, int* __restrict__ cnts) {
    __shared__ __align__(16) unsigned smem[64 * FS];   // 33.8 KB: W tile / hist cnts
    int t = threadIdx.x;

    if (blockIdx.x >= NGB) {
        // ---------------- histogram branch (dst AND src), int4 edge loads --------
        int* hd = (int*)smem;
        int* hs = hd + NBUCK;
        int b = blockIdx.x - NGB;
        for (int k = t; k < NBUCK; k += 256) { hd[k] = 0; hs[k] = 0; }
        __syncthreads();
        int base = b * EPB, end = base + EPB;
        int a0 = (base + 3) & ~3;              // first 16B-aligned index
        int a1 = end & ~3;                     // aligned end
        if (t < a0 - base) {
            int i = base + t;
            atomicAdd(&hd[dst[i] >> 8], 1);
            atomicAdd(&hs[src[i] >> 8], 1);
        }
        for (int i = a0 + 4 * t; i < a1; i += 1024) {
            int4 d4 = *(const int4*)&dst[i];
            int4 s4 = *(const int4*)&src[i];
            atomicAdd(&hd[d4.x >> 8], 1); atomicAdd(&hd[d4.y >> 8], 1);
            atomicAdd(&hd[d4.z >> 8], 1); atomicAdd(&hd[d4.w >> 8], 1);
            atomicAdd(&hs[s4.x >> 8], 1); atomicAdd(&hs[s4.y >> 8], 1);
            atomicAdd(&hs[s4.z >> 8], 1); atomicAdd(&hs[s4.w >> 8], 1);
        }
        if (t < end - a1) {
            int i = a1 + t;
            atomicAdd(&hd[dst[i] >> 8], 1);
            atomicAdd(&hs[src[i] >> 8], 1);
        }
        __syncthreads();
        for (int k = t; k < NBUCK; k += 256) {
            cntd[k * PB + b] = hd[k];
            cnts[k * PB + b] = hs[k];
        }
        return;
    }

    // ---------------- GEMM branch: h(fp16) = feat@W^T, fused el/er ---------------
    unsigned* wlds = smem;                     // 64 outf x 128 k, packed
    int n0 = blockIdx.x * 64;

    int lane = t & 63, wv_ = t >> 6;
    int quad = lane >> 4, nl = lane & 15;
    int mrow = wv_ * 16 + nl;                  // A-operand node row for this lane
    int g = n0 + mrow;

    // issue all A-fragment loads up front (latency overlaps W staging below)
    const float* frow = &feat[(size_t)g * IN_F];
    float4 fa[4][2];
    #pragma unroll
    for (int ks = 0; ks < 4; ++ks) {
        int ko = ks * 32 + quad * 8;
        if (g < N_NODES) {
            fa[ks][0] = *(const float4*)(frow + ko);
            fa[ks][1] = *(const float4*)(frow + ko + 4);
        } else {
            fa[ks][0] = (float4){0.f, 0.f, 0.f, 0.f};
            fa[ks][1] = (float4){0.f, 0.f, 0.f, 0.f};
        }
    }

    #pragma unroll
    for (int j = 0; j < 8; ++j) {              // 2048 float4-quads for W
        int idx = t + j * 256;
        int row = idx >> 5, k4 = (idx & 31) * 4;
        float4 wv = *(const float4*)&W[row * IN_F + k4];
        unsigned* wp = &wlds[row * FS + k4];
        wp[0] = pack_bf(wv.x); wp[1] = pack_bf(wv.y);
        wp[2] = pack_bf(wv.z); wp[3] = pack_bf(wv.w);
    }
    __syncthreads();

    f32x4 acc[4];
    #pragma unroll
    for (int nt = 0; nt < 4; ++nt) acc[nt] = (f32x4){0.f, 0.f, 0.f, 0.f};

    #pragma unroll
    for (int ks = 0; ks < 4; ++ks) {
        int ko = ks * 32 + quad * 8;
        float ff[8] = {fa[ks][0].x, fa[ks][0].y, fa[ks][0].z, fa[ks][0].w,
                       fa[ks][1].x, fa[ks][1].y, fa[ks][1].z, fa[ks][1].w};
        short8 ahi, alo;
        #pragma unroll
        for (int q2 = 0; q2 < 8; ++q2) {
            unsigned u  = __float_as_uint(ff[q2]);
            unsigned hi = u & 0xffff0000u;
            float    lo = ff[q2] - __uint_as_float(hi);
            ahi[q2] = (short)(hi >> 16);
            alo[q2] = (short)(__float_as_uint(lo) >> 16);
        }
        #pragma unroll
        for (int nt = 0; nt < 4; ++nt) {
            const uint4* bp = (const uint4*)&wlds[(nt * 16 + nl) * FS + ko];
            uint4 b0 = bp[0], b1 = bp[1];
            short8 bhi, blo; unpack8(b0, b1, bhi, blo);
            acc[nt] = __builtin_amdgcn_mfma_f32_16x16x32_bf16(ahi, bhi, acc[nt], 0, 0, 0);
            acc[nt] = __builtin_amdgcn_mfma_f32_16x16x32_bf16(ahi, blo, acc[nt], 0, 0, 0);
            acc[nt] = __builtin_amdgcn_mfma_f32_16x16x32_bf16(alo, bhi, acc[nt], 0, 0, 0);
        }
    }

    float al4[4], ar4[4];
    #pragma unroll
    for (int nt = 0; nt < 4; ++nt) { al4[nt] = attn_l[nt * 16 + nl]; ar4[nt] = attn_r[nt * 16 + nl]; }
    float elp[4] = {0.f, 0.f, 0.f, 0.f}, erp[4] = {0.f, 0.f, 0.f, 0.f};
    #pragma unroll
    for (int nt = 0; nt < 4; ++nt)
        #pragma unroll
        for (int r = 0; r < 4; ++r) {
            elp[r] += acc[nt][r] * al4[nt];
            erp[r] += acc[nt][r] * ar4[nt];
        }
    #pragma unroll
    for (int off = 1; off <= 8; off <<= 1)
        #pragma unroll
        for (int r = 0; r < 4; ++r) {
            elp[r] += __shfl_xor(elp[r], off);
            erp[r] += __shfl_xor(erp[r], off);
        }
    int gbase = n0 + wv_ * 16 + quad * 4;
    if (nl == 0) {
        #pragma unroll
        for (int r = 0; r < 4; ++r) {
            int gg = gbase + r;
            if (gg < N_NODES) { el[gg] = elp[r]; er[gg] = erp[r]; }
        }
    }
    #pragma unroll
    for (int r = 0; r < 4; ++r) {
        int gg = gbase + r;
        if (gg < N_NODES) {
            #pragma unroll
            for (int nt = 0; nt < 4; ++nt)
                h16[(size_t)gg * OUT_F + nt * 16 + nl] = __float2half(acc[nt][r]);
        }
    }
}

// ---------------- bucket totals = column sums of count matrices -------------------
__global__ __launch_bounds__(256) void k_colsum(const int* __restrict__ cntd,
                                                const int* __restrict__ cnts,
                                                int* __restrict__ totd,
                                                int* __restrict__ tots) {
    __shared__ int s[256];
    int b = blockIdx.x, t = threadIdx.x;
    const int* m; int* o; int k;
    if (b < NBUCK) { m = cntd; o = totd; k = b; }
    else           { m = cnts; o = tots; k = b - NBUCK; }
    s[t] = m[k * PB + t] + m[k * PB + t + 256];
    __syncthreads();
    for (int d = 128; d; d >>= 1) { if (t < d) s[t] += s[t + d]; __syncthreads(); }
    if (t == 0) o[k] = s[0];
}

// ---------------- exclusive scans of bucket totals (both keys) --------------------
__global__ __launch_bounds__(512) void k_bstart(const int* __restrict__ totd,
                                                const int* __restrict__ tots,
                                                int* bstartd, int* bstarts) {
    __shared__ int s[512];
    int t = threadIdx.x;
    int v = (t < NBUCK) ? totd[t] : 0;
    s[t] = v; __syncthreads();
    for (int d = 1; d < 512; d <<= 1) { int a = (t >= d) ? s[t - d] : 0; __syncthreads(); s[t] += a; __syncthreads(); }
    if (t <= NBUCK) bstartd[t] = s[t] - v;
    __syncthreads();
    int v2 = (t < NBUCK) ? tots[t] : 0;
    s[t] = v2; __syncthreads();
    for (int d = 1; d < 512; d <<= 1) { int a = (t >= d) ? s[t - d] : 0; __syncthreads(); s[t] += a; __syncthreads(); }
    if (t <= NBUCK) bstarts[t] = s[t] - v2;
}

// ---------------- per-(bucket,block) offsets, in place, both matrices -------------
__global__ __launch_bounds__(512) void k_blockoff(const int* __restrict__ bstartd,
                                                  const int* __restrict__ bstarts,
                                                  int* cntd, int* cnts) {
    __shared__ int s[512];
    int b = blockIdx.x, t = threadIdx.x;
    int* m; const int* bs; int k;
    if (b < NBUCK) { m = cntd; bs = bstartd; k = b; }
    else           { m = cnts; bs = bstarts; k = b - NBUCK; }
    int c = m[k * PB + t];
    s[t] = c; __syncthreads();
    for (int d = 1; d < 512; d <<= 1) { int a = (t >= d) ? s[t - d] : 0; __syncthreads(); s[t] += a; __syncthreads(); }
    m[k * PB + t] = bs[k] + s[t] - c;
}

// ---------------- merged scatter: LDS dense staging + coalesced copy-out ----------
__global__ __launch_bounds__(256) void k_scatter3(
        const int* __restrict__ src, const int* __restrict__ dst,
        const float* __restrict__ el, const float* __restrict__ er,
        const int* __restrict__ offd, const int* __restrict__ offs,
        int2* __restrict__ tmpd, unsigned char* __restrict__ tmps) {
    __shared__ int gOffD[NBUCK], gOffS[NBUCK];
    __shared__ int hD[NBUCK], hS[NBUCK];
    __shared__ int fD[NBUCK], fS[NBUCK];
    __shared__ int sD[512], sS[512];
    __shared__ int2 stD[EPB];
    __shared__ unsigned char stS[EPB];
    int t = threadIdx.x, b = blockIdx.x;
    for (int k = t; k < NBUCK; k += 256) {
        gOffD[k] = offd[k * PB + b]; gOffS[k] = offs[k * PB + b];
        hD[k] = 0; hS[k] = 0; fD[k] = 0; fS[k] = 0;
    }
    __syncthreads();
    int base = b * EPB;
    for (int i = t; i < EPB; i += 256) {
        atomicAdd(&hD[dst[base + i] >> 8], 1);
        atomicAdd(&hS[src[base + i] >> 8], 1);
    }
    __syncthreads();
    sD[t]       = (t < NBUCK) ? hD[t] : 0;
    sD[t + 256] = (t + 256 < NBUCK) ? hD[t + 256] : 0;
    sS[t]       = (t < NBUCK) ? hS[t] : 0;
    sS[t + 256] = (t + 256 < NBUCK) ? hS[t + 256] : 0;
    __syncthreads();
    for (int d = 1; d < 512; d <<= 1) {
        int a0 = (t >= d) ? sD[t - d] : 0;
        int a1 = sD[t + 256 - d];
        int b0 = (t >= d) ? sS[t - d] : 0;
        int b1 = sS[t + 256 - d];
        __syncthreads();
        sD[t] += a0; sD[t + 256] += a1;
        sS[t] += b0; sS[t + 256] += b1;
        __syncthreads();
    }
    for (int k = t; k < NBUCK; k += 256) {
        hD[k] = sD[k] - hD[k];
        hS[k] = sS[k] - hS[k];
    }
    __syncthreads();
    for (int i = t; i < EPB; i += 256) {
        int e = base + i;
        int sN = src[e], dN = dst[e];
        int ks = sN >> 8;
        int rs = atomicAdd(&fS[ks], 1);
        stS[hS[ks] + rs] = (unsigned char)(sN & 255);
        float v = el[sN] + er[dN];
        v = (v > 0.f) ? v : NEG_SLOPE * v;
        float pe = __expf(v);
        int kd = dN >> 8;
        int rd = atomicAdd(&fD[kd], 1);
        int2 rec; rec.x = sN | ((dN & 255) << 17); rec.y = __float_as_int(pe);
        stD[hD[kd] + rd] = rec;
    }
    __syncthreads();
    for (int j = t; j < EPB; j += 256) {
        int k = 0;
        #pragma unroll
        for (int step = 256; step > 0; step >>= 1) {
            int c = k + step;
            if (c <= 511 && sD[c - 1] <= j) k = c;
        }
        tmpd[gOffD[k] + (j - hD[k])] = stD[j];
        int k2 = 0;
        #pragma unroll
        for (int step = 256; step > 0; step >>= 1) {
            int c = k2 + step;
            if (c <= 511 && sS[c - 1] <= j) k2 = c;
        }
        tmps[gOffS[k2] + (j - hS[k2])] = stS[j];
    }
}

// ---------------- src-bucket count -> onorm ---------------------------------------
// v12: 512 threads (was 256). 391-block grid gave only 1564 waves (~19% occupancy)
// for a latency-bound loop; doubling block size doubles waves in flight. The
// 256-entry table stays 256-wide (t<256 guards).
__global__ __launch_bounds__(512) void k_srccnt(
        const unsigned char* __restrict__ tmps, const int* __restrict__ bstarts,
        float* __restrict__ onorm) {
    __shared__ int cnt[256];
    int k = blockIdx.x, t = threadIdx.x;
    if (t < 256) cnt[t] = 0;
    __syncthreads();
    int base = bstarts[k], end = bstarts[k + 1];
    for (int i = base + t; i < end; i += 512)
        atomicAdd(&cnt[tmps[i]], 1);
    __syncthreads();
    if (t < 256) {
        int idx = k * 256 + t;
        if (idx < N_NODES) onorm[idx] = rsqrtf((float)max(cnt[t], 1));
    }
}

// ---------------- per-bucket fine sort -> CSR {src, pexp*onorm[src]}, sigma -------
// v12: 512 threads for the same occupancy reason (19% -> ~38%). Count/scan tables
// remain 256-wide under t<256 guards; record loops stride 512. Within-bucket
// placement is atomic-arrival-order (as before); absmax is pinned at the fp16
// quantization floor so this reordering class is tolerance-neutral.
__global__ __launch_bounds__(512) void k_bucket(
        const int2* __restrict__ tmp, const int* __restrict__ bstart,
        const float* __restrict__ onorm, float2* __restrict__ csr,
        int* __restrict__ rowstart, float* __restrict__ sigma) {
    __shared__ int   cs[256];
    __shared__ int   excl[256];
    __shared__ int   fill[256];
    __shared__ float dsum[256];
    __shared__ float2 stC[BCAP];               // 40 KB csr staging
    int k = blockIdx.x, t = threadIdx.x;
    int base = bstart[k], end = bstart[k + 1];
    int tot = end - base;
    bool staged = (tot <= BCAP);
    if (t < 256) { cs[t] = 0; fill[t] = 0; dsum[t] = 0.f; }
    __syncthreads();
    for (int i = base + t; i < end; i += 512)
        atomicAdd(&cs[(tmp[i].x >> 17) & 255], 1);
    __syncthreads();
    int c = (t < 256) ? cs[t] : 0;
    for (int d = 1; d < 256; d <<= 1) {
        int a = (t < 256 && t >= d) ? cs[t - d] : 0;
        __syncthreads();
        if (t < 256) cs[t] += a;
        __syncthreads();
    }
    if (t < 256) excl[t] = cs[t] - c;
    __syncthreads();
    int idx = k * 256 + t;
    if (t < 256 && idx <= N_NODES) rowstart[idx] = base + excl[t];
    for (int i = base + t; i < end; i += 512) {
        int2 rec = tmp[i];
        int dlow = (rec.x >> 17) & 255;
        int r = atomicAdd(&fill[dlow], 1);
        float pe = __int_as_float(rec.y);
        int sN = rec.x & 131071;
        float2 w;
        w.x = __int_as_float(sN);
        w.y = pe * onorm[sN];
        int pos = excl[dlow] + r;
        if (staged) stC[pos] = w;
        else        csr[base + pos] = w;
        atomicAdd(&dsum[dlow], pe);
    }
    __syncthreads();
    if (staged)
        for (int j = t; j < tot; j += 512)
            csr[base + j] = stC[j];            // coalesced full-line stores
    if (t < 256 && idx < N_NODES) {
        float inn = sqrtf((float)max(c, 1));
        sigma[idx] = (c > 0) ? inn / dsum[t] : 0.f;
    }
}

// ---------------- SpMM hop: y[d] = sigma[d] * sum_e val_e * x[col_e] --------------
// v3 geometry (proven best; r4 ILP-up, r8 degree-sort, r11 reg-capped cooperative
// all regressed): 8 lanes/node, 16B dwordx4 gather per lane, 8 nodes/wave x 8-edge
// unroll = 64 lines in flight/wave at 12500 waves. f32 accumulate. NO second
// launch_bounds arg (r11: min-waves cap 32 VGPR -> scratch spill -> 12x).
// OT = __half (hops 1,2) or float (hop 3).
template<typename OT>
__global__ __launch_bounds__(256) void k_spmm(
        const __half* __restrict__ x, const int* __restrict__ rowstart,
        const float2* __restrict__ csr, const float* __restrict__ sigma,
        OT* __restrict__ y) {
    int node = blockIdx.x * 32 + (threadIdx.x >> 3);
    int fl = threadIdx.x & 7;
    if (node >= N_NODES) return;
    int b = rowstart[node], e = rowstart[node + 1];
    float4 a0lo = {0.f, 0.f, 0.f, 0.f}, a0hi = {0.f, 0.f, 0.f, 0.f};
    float4 a1lo = {0.f, 0.f, 0.f, 0.f}, a1hi = {0.f, 0.f, 0.f, 0.f};
    for (int i = b; i < e; i += 8) {
        #pragma unroll
        for (int u = 0; u < 8; ++u) {
            int j = i + u;
            int jc = (j < e) ? j : (e - 1);
            float2 w = csr[jc];                    // 8-lane broadcast (8B)
            float vv = (j < e) ? w.y : 0.f;
            unsigned boff = ((unsigned)__float_as_int(w.x) << 7) | ((unsigned)fl << 4);
            uint4 pk = *(const uint4*)((const char*)x + boff);
            float2 f0 = __half22float2(*(__half2*)&pk.x);
            float2 f1 = __half22float2(*(__half2*)&pk.y);
            float2 f2 = __half22float2(*(__half2*)&pk.z);
            float2 f3 = __half22float2(*(__half2*)&pk.w);
            float4& alo = (u & 1) ? a1lo : a0lo;
            float4& ahi = (u & 1) ? a1hi : a0hi;
            alo.x += vv * f0.x; alo.y += vv * f0.y; alo.z += vv * f1.x; alo.w += vv * f1.y;
            ahi.x += vv * f2.x; ahi.y += vv * f2.y; ahi.z += vv * f3.x; ahi.w += vv * f3.y;
        }
    }
    float sg = sigma[node];
    float4 rlo, rhi;
    rlo.x = sg * (a0lo.x + a1lo.x); rlo.y = sg * (a0lo.y + a1lo.y);
    rlo.z = sg * (a0lo.z + a1lo.z); rlo.w = sg * (a0lo.w + a1lo.w);
    rhi.x = sg * (a0hi.x + a1hi.x); rhi.y = sg * (a0hi.y + a1hi.y);
    rhi.z = sg * (a0hi.z + a1hi.z); rhi.w = sg * (a0hi.w + a1hi.w);
    if constexpr (sizeof(OT) == 4) {
        float* yp = (float*)y + (size_t)node * OUT_F + fl * 8;
        *(float4*)yp       = rlo;
        *(float4*)(yp + 4) = rhi;
    } else {
        __half2 p0 = __floats2half2_rn(rlo.x, rlo.y);
        __half2 p1 = __floats2half2_rn(rlo.z, rlo.w);
        __half2 p2 = __floats2half2_rn(rhi.x, rhi.y);
        __half2 p3 = __floats2half2_rn(rhi.z, rhi.w);
        uint4 o;
        o.x = *(unsigned*)&p0; o.y = *(unsigned*)&p1;
        o.z = *(unsigned*)&p2; o.w = *(unsigned*)&p3;
        *(uint4*)((__half*)y + (size_t)node * OUT_F + fl * 8) = o;
    }
}

extern "C" void kernel_launch(void* const* d_in, const int* in_sizes, int n_in,
                              void* d_out, int out_size, void* d_ws, size_t ws_size,
                              hipStream_t stream) {
    const float* feat   = (const float*)d_in[0];
    const float* W      = (const float*)d_in[1];
    const float* attn_l = (const float*)d_in[2];
    const float* attn_r = (const float*)d_in[3];
    const int*   src    = (const int*)d_in[4];
    const int*   dst    = (const int*)d_in[5];
    float* out = (float*)d_out;

    char* p = (char*)d_ws;
    auto alloc = [&](size_t bytes) {
        void* r = (void*)p;
        p += (bytes + 255) & ~(size_t)255;
        return r;
    };
    // region1: hbuf (fp16, 12.8 MB): gemm out -> hop1 in; then y2 (hop2 out, hop3 in).
    __half* hbuf = (__half*)alloc((size_t)N_NODES * OUT_F * 2);
    // region2 (14.4 MB): tmpd (12.8) + tmps (1.6) until k_bucket/srccnt; then A = y1.
    char* r2 = (char*)alloc((size_t)N_EDGES * 8 + (size_t)N_EDGES);
    int2*  tmpd = (int2*)r2;
    unsigned char* tmps = (unsigned char*)(r2 + (size_t)N_EDGES * 8);
    __half* A   = (__half*)r2;

    float2* csr      = (float2*)alloc((size_t)N_EDGES * 8);        // 12.8 MB
    int*    cntd     = (int*)   alloc((size_t)NBUCK * PB * 4);
    int*    cnts     = (int*)   alloc((size_t)NBUCK * PB * 4);
    int*    totd     = (int*)   alloc(NBUCK * 4);
    int*    tots     = (int*)   alloc(NBUCK * 4);
    int*    bstartd  = (int*)   alloc((NBUCK + 1) * 4);
    int*    bstarts  = (int*)   alloc((NBUCK + 1) * 4);
    int*    rowstart = (int*)   alloc((N_NODES + 1) * 4);
    float*  onorm    = (float*) alloc(N_NODES * 4);
    float*  sigma    = (float*) alloc(N_NODES * 4);
    float*  el       = (float*) alloc(N_NODES * 4);
    float*  er       = (float*) alloc(N_NODES * 4);

    k_gemm_hist<<<NGB + PB,   256, 0, stream>>>(feat, W, attn_l, attn_r, hbuf, el, er,
                                                src, dst, cntd, cnts);
    k_colsum   <<<2 * NBUCK,  256, 0, stream>>>(cntd, cnts, totd, tots);
    k_bstart   <<<1,          512, 0, stream>>>(totd, tots, bstartd, bstarts);
    k_blockoff <<<2 * NBUCK,  512, 0, stream>>>(bstartd, bstarts, cntd, cnts);
    k_scatter3 <<<PB,         256, 0, stream>>>(src, dst, el, er, cntd, cnts, tmpd, tmps);
    k_srccnt   <<<NBUCK,      512, 0, stream>>>(tmps, bstarts, onorm);
    k_bucket   <<<NBUCK,      512, 0, stream>>>(tmpd, bstartd, onorm, csr, rowstart, sigma);

    const int nb_spmm = (N_NODES + 31) / 32;   // one 8-lane group per node
    k_spmm<__half><<<nb_spmm, 256, 0, stream>>>(hbuf, rowstart, csr, sigma, A);    // hop 1
    k_spmm<__half><<<nb_spmm, 256, 0, stream>>>(A,    rowstart, csr, sigma, hbuf); // hop 2
    k_spmm<float> <<<nb_spmm, 256, 0, stream>>>(hbuf, rowstart, csr, sigma, out);  // hop 3
}